// Round 1
// baseline (52.891 us; speedup 1.0000x reference)
//
#include <hip/hip_runtime.h>

#define NB 8
#define C_IN 64
#define HW 65536      // 256*256
#define CF 256
#define FHW 4096      // 64*64
#define NSEG 256

// ws layout (floats):
// [0, 32768)                 featsum[NB][FHW]
// [32768, 32768+2048)        seg_in [NB][NSEG]
// [+2048)                    seg_feat[NB][NSEG]
// [+2048)                    seg_cnt[NB][NSEG]
// [+32)                      pair partials [32]

__global__ void featsum_kernel(const float* __restrict__ feat,
                               float* __restrict__ featsum) {
    int b = blockIdx.y, cg = blockIdx.z;
    int p = blockIdx.x * 256 + threadIdx.x;
    const float* f = feat + ((size_t)(b * CF + cg * 32)) * FHW + p;
    float s = 0.f;
#pragma unroll
    for (int c = 0; c < 32; ++c) s += f[(size_t)c * FHW];
    atomicAdd(&featsum[b * FHW + p], s);
}

__global__ __launch_bounds__(256) void main_kernel(
    const float* __restrict__ input, const int* __restrict__ sp,
    const float* __restrict__ featsum, float* __restrict__ seg) {
    __shared__ float fls[FHW];
    __shared__ float bin_in[NSEG], bin_feat[NSEG], bin_cnt[NSEG];
    int b = blockIdx.y;
    int t = threadIdx.x;
    for (int i = t; i < FHW; i += 256) fls[i] = featsum[b * FHW + i];
    bin_in[t] = 0.f; bin_feat[t] = 0.f; bin_cnt[t] = 0.f;
    __syncthreads();

    int p0 = blockIdx.x * 1024 + t * 4;
    int v0 = p0 >> 2;
    const float4* in4 = (const float4*)(input + (size_t)b * C_IN * HW);
    float4 xs = make_float4(0.f, 0.f, 0.f, 0.f);
#pragma unroll
    for (int c = 0; c < C_IN; ++c) {
        float4 v = in4[(size_t)c * (HW / 4) + v0];
        xs.x += v.x; xs.y += v.y; xs.z += v.z; xs.w += v.w;
    }
    int4 sv = ((const int4*)(sp + (size_t)b * HW))[v0];

    int y = p0 >> 8;                       // 4 consecutive pixels share the row
    float cy = (float)y * (63.0f / 255.0f);
    int iy = (int)cy; float ty = cy - (float)iy; int iy1 = min(iy + 1, 63);
    float xsv[4] = {xs.x, xs.y, xs.z, xs.w};
    int   ssv[4] = {sv.x, sv.y, sv.z, sv.w};
#pragma unroll
    for (int k = 0; k < 4; ++k) {
        int x = (p0 + k) & 255;
        float cx = (float)x * (63.0f / 255.0f);
        int ix = (int)cx; float tx = cx - (float)ix; int ix1 = min(ix + 1, 63);
        float f00 = fls[iy * 64 + ix],  f10 = fls[iy1 * 64 + ix];
        float f01 = fls[iy * 64 + ix1], f11 = fls[iy1 * 64 + ix1];
        float a0 = f00 * (1.f - ty) + f10 * ty;
        float a1 = f01 * (1.f - ty) + f11 * ty;
        float fs = a0 * (1.f - tx) + a1 * tx;
        int s = ssv[k];
        atomicAdd(&bin_in[s], xsv[k]);
        atomicAdd(&bin_feat[s], fs);
        atomicAdd(&bin_cnt[s], 1.f);
    }
    __syncthreads();
    atomicAdd(&seg[b * NSEG + t], bin_in[t]);
    atomicAdd(&seg[NB * NSEG + b * NSEG + t], bin_feat[t]);
    atomicAdd(&seg[2 * NB * NSEG + b * NSEG + t], bin_cnt[t]);
}

__global__ void pair_kernel(const float* __restrict__ seg,
                            float* __restrict__ pp) {
    __shared__ float m1[NSEG], m2[NSEG];
    __shared__ float wsum[4];
    int b = blockIdx.y, ig = blockIdx.x, t = threadIdx.x;
    float cnt = seg[2 * NB * NSEG + b * NSEG + t];
    m1[t] = seg[b * NSEG + t] / (cnt * 64.0f);
    m2[t] = seg[NB * NSEG + b * NSEG + t] / (cnt * 256.0f);
    __syncthreads();
    int i = ig * 64 + (t & 63);
    int j0 = (t >> 6) * 64;
    float a1 = m1[i], a2 = m2[i];
    float acc = 0.f;
#pragma unroll 8
    for (int jj = 0; jj < 64; ++jj) {
        int j = j0 + jj;
        acc += fabsf(fabsf(a1 - m1[j]) - fabsf(a2 - m2[j]));
    }
    for (int off = 32; off; off >>= 1) acc += __shfl_down(acc, off);
    if ((t & 63) == 0) wsum[t >> 6] = acc;
    __syncthreads();
    if (t == 0) pp[b * 4 + ig] = wsum[0] + wsum[1] + wsum[2] + wsum[3];
}

__global__ void final_kernel(const float* __restrict__ pp,
                             float* __restrict__ out) {
    int t = threadIdx.x;   // 64 threads
    float v = (t < 32) ? pp[t] : 0.f;
    for (int off = 32; off; off >>= 1) v += __shfl_down(v, off);
    if (t == 0) out[0] = v / 524288.0f;   // NB * NSEG * NSEG
}

extern "C" void kernel_launch(void* const* d_in, const int* in_sizes, int n_in,
                              void* d_out, int out_size, void* d_ws, size_t ws_size,
                              hipStream_t stream) {
    const float* input   = (const float*)d_in[0];
    const float* feature = (const float*)d_in[1];
    const int*   sp      = (const int*)d_in[2];
    float* ws = (float*)d_ws;
    float* featsum = ws;
    float* seg     = ws + NB * FHW;
    float* pp      = seg + 3 * NB * NSEG;

    hipMemsetAsync(d_ws, 0, (size_t)(NB * FHW + 3 * NB * NSEG + 32) * sizeof(float), stream);
    featsum_kernel<<<dim3(16, 8, 8), 256, 0, stream>>>(feature, featsum);
    main_kernel<<<dim3(64, 8), 256, 0, stream>>>(input, sp, featsum, seg);
    pair_kernel<<<dim3(4, 8), 256, 0, stream>>>(seg, pp);
    final_kernel<<<1, 64, 0, stream>>>(pp, (float*)d_out);
}

// Round 2
// 49.785 us; speedup vs baseline: 1.0624x; 1.0624x over previous
//
#include <hip/hip_runtime.h>

#define NB 8
#define C_IN 64
#define HW 65536      // 256*256
#define CF 256
#define FHW 4096      // 64*64
#define NSEG 256
#define NGRP 8        // channel groups in featsum (32 ch each)
#define MBLK 64       // main_kernel blocks per batch

// ws layout (floats):
// [0, 262144)                partial[NB][NGRP][FHW]        (1 MiB)
// [262144, 262144+393216)    seg_part[NB][MBLK][3][NSEG]   (1.5 MiB)
// [+8]                       pp[NB]

__global__ void featsum_kernel(const float* __restrict__ feat,
                               float* __restrict__ partial) {
    int b = blockIdx.y, g = blockIdx.z;
    int q = blockIdx.x * 256 + threadIdx.x;           // float4 index in [0,1024)
    const float4* f4 = (const float4*)(feat + ((size_t)(b * CF + g * 32)) * FHW);
    float4 s = make_float4(0.f, 0.f, 0.f, 0.f);
#pragma unroll
    for (int c = 0; c < 32; ++c) {
        float4 v = f4[(size_t)c * (FHW / 4) + q];
        s.x += v.x; s.y += v.y; s.z += v.z; s.w += v.w;
    }
    ((float4*)partial)[(size_t)(b * NGRP + g) * (FHW / 4) + q] = s;
}

__global__ __launch_bounds__(256) void main_kernel(
    const float* __restrict__ input, const int* __restrict__ sp,
    const float* __restrict__ partial, float* __restrict__ seg_part) {
    __shared__ float fls[FHW];
    __shared__ float bin[3][NSEG];
    int b = blockIdx.y;
    int t = threadIdx.x;
    // LDS tile: sum the 8 channel-group partials (L2-resident)
    const float4* p4 = (const float4*)(partial + (size_t)b * NGRP * FHW);
    for (int i = t; i < FHW / 4; i += 256) {
        float4 s = p4[i];
#pragma unroll
        for (int g = 1; g < NGRP; ++g) {
            float4 v = p4[g * (FHW / 4) + i];
            s.x += v.x; s.y += v.y; s.z += v.z; s.w += v.w;
        }
        ((float4*)fls)[i] = s;
    }
    bin[0][t] = 0.f; bin[1][t] = 0.f; bin[2][t] = 0.f;
    __syncthreads();

    int p0 = blockIdx.x * 1024 + t * 4;
    int v0 = blockIdx.x * 256 + t;
    const float4* in4 = (const float4*)(input + (size_t)b * C_IN * HW);
    float4 xs = make_float4(0.f, 0.f, 0.f, 0.f);
#pragma unroll
    for (int c = 0; c < C_IN; ++c) {
        float4 v = in4[(size_t)c * (HW / 4) + v0];
        xs.x += v.x; xs.y += v.y; xs.z += v.z; xs.w += v.w;
    }
    int4 sv = ((const int4*)(sp + (size_t)b * HW))[v0];

    int y = p0 >> 8;                       // 4 consecutive pixels share the row
    float cy = (float)y * (63.0f / 255.0f);
    int iy = (int)cy; float ty = cy - (float)iy; int iy1 = min(iy + 1, 63);
    float xsv[4] = {xs.x, xs.y, xs.z, xs.w};
    int   ssv[4] = {sv.x, sv.y, sv.z, sv.w};
#pragma unroll
    for (int k = 0; k < 4; ++k) {
        int x = (p0 + k) & 255;
        float cx = (float)x * (63.0f / 255.0f);
        int ix = (int)cx; float tx = cx - (float)ix; int ix1 = min(ix + 1, 63);
        float f00 = fls[iy * 64 + ix],  f10 = fls[iy1 * 64 + ix];
        float f01 = fls[iy * 64 + ix1], f11 = fls[iy1 * 64 + ix1];
        float a0 = f00 * (1.f - ty) + f10 * ty;
        float a1 = f01 * (1.f - ty) + f11 * ty;
        float fs = a0 * (1.f - tx) + a1 * tx;
        int s = ssv[k];
        atomicAdd(&bin[0][s], xsv[k]);
        atomicAdd(&bin[1][s], fs);
        atomicAdd(&bin[2][s], 1.f);
    }
    __syncthreads();
    float* sb = seg_part + (size_t)(b * MBLK + blockIdx.x) * 3 * NSEG;
    sb[t]            = bin[0][t];
    sb[NSEG + t]     = bin[1][t];
    sb[2 * NSEG + t] = bin[2][t];
}

__global__ __launch_bounds__(1024) void pair_kernel(
    const float* __restrict__ seg_part, float* __restrict__ pp) {
    __shared__ float s3[3 * NSEG];
    __shared__ float m1[NSEG], m2[NSEG];
    __shared__ float red[16];
    int b = blockIdx.x, t = threadIdx.x;
    if (t < 3 * NSEG) {
        float s = 0.f;
        const float* base = seg_part + (size_t)b * MBLK * 3 * NSEG + t;
#pragma unroll 8
        for (int k = 0; k < MBLK; ++k) s += base[(size_t)k * 3 * NSEG];
        s3[t] = s;
    }
    __syncthreads();
    if (t < NSEG) {
        float cnt = s3[2 * NSEG + t];
        m1[t] = s3[t] / (cnt * 64.0f);
        m2[t] = s3[NSEG + t] / (cnt * 256.0f);
    }
    __syncthreads();
    int i = t & 255;
    int j0 = (t >> 8) * 64;
    float a1 = m1[i], a2 = m2[i];
    float acc = 0.f;
#pragma unroll 8
    for (int jj = 0; jj < 64; ++jj) {
        int j = j0 + jj;
        acc += fabsf(fabsf(a1 - m1[j]) - fabsf(a2 - m2[j]));
    }
#pragma unroll
    for (int off = 32; off; off >>= 1) acc += __shfl_down(acc, off);
    if ((t & 63) == 0) red[t >> 6] = acc;
    __syncthreads();
    if (t == 0) {
        float s = 0.f;
#pragma unroll
        for (int w = 0; w < 16; ++w) s += red[w];
        pp[b] = s;
    }
}

__global__ void final_kernel(const float* __restrict__ pp,
                             float* __restrict__ out) {
    int t = threadIdx.x;   // 64 threads
    float v = (t < NB) ? pp[t] : 0.f;
#pragma unroll
    for (int off = 4; off; off >>= 1) v += __shfl_down(v, off);
    if (t == 0) out[0] = v / 524288.0f;   // NB * NSEG * NSEG
}

extern "C" void kernel_launch(void* const* d_in, const int* in_sizes, int n_in,
                              void* d_out, int out_size, void* d_ws, size_t ws_size,
                              hipStream_t stream) {
    const float* input   = (const float*)d_in[0];
    const float* feature = (const float*)d_in[1];
    const int*   sp      = (const int*)d_in[2];
    float* ws = (float*)d_ws;
    float* partial  = ws;
    float* seg_part = ws + (size_t)NB * NGRP * FHW;
    float* pp       = seg_part + (size_t)NB * MBLK * 3 * NSEG;

    featsum_kernel<<<dim3(4, 8, 8), 256, 0, stream>>>(feature, partial);
    main_kernel<<<dim3(MBLK, 8), 256, 0, stream>>>(input, sp, partial, seg_part);
    pair_kernel<<<dim3(8), 1024, 0, stream>>>(seg_part, pp);
    final_kernel<<<1, 64, 0, stream>>>(pp, (float*)d_out);
}